// Round 19
// baseline (63.609 us; speedup 1.0000x reference)
//
#include <hip/hip_runtime.h>
#include <hip/hip_bf16.h>

typedef __attribute__((ext_vector_type(8))) short bf16x8;
typedef __attribute__((ext_vector_type(4))) float float4_t;
typedef __attribute__((ext_vector_type(16))) float f32x16;
typedef __attribute__((ext_vector_type(4))) int int4v;
typedef __attribute__((ext_vector_type(2))) int int2v;

constexpr int Lseq = 2048;
constexpr int ROWS = 1024;   // H*D floats between consecutive l for fixed (n,h)
constexpr float SCALE_LOG2E = 0.18033688011112042f;  // (1/sqrt(64))*log2(e)

// Fragment-major bf16 sub-images: per (nh, 64-row subtile): 512 frags x 16B = 8 KB.
// frag f = half*256 + c*64 + hi*32 + lq; K elem = K[sub*64+half*32+lq][c*16+hi*8+j],
// V elem = V^T[half*32+lq][c*16+hi*8+j] (rows=d, cols=kv within subtile).
__device__ short g_Kb[32 * 32 * 4096];   // 8 MB
__device__ short g_Vb[32 * 32 * 4096];   // 8 MB

__device__ __forceinline__ int cvtpk(float lo, float hi) {
  int r; asm("v_cvt_pk_bf16_f32 %0, %1, %2" : "=v"(r) : "v"(lo), "v"(hi)); return r;
}
__device__ __forceinline__ void plswap(int& a, int& b) {
  int2v r = __builtin_amdgcn_permlane32_swap(a, b, false, false);
  a = r[0]; b = r[1];
}
__device__ __forceinline__ int4v pk8(float4_t a, float4_t b) {
  int4v t;
  t[0] = cvtpk(a[0], a[1]); t[1] = cvtpk(a[2], a[3]);
  t[2] = cvtpk(b[0], b[1]); t[3] = cvtpk(b[2], b[3]);
  return t;
}
__device__ __forceinline__ void dma16(const void* g, void* l) {
  __builtin_amdgcn_global_load_lds(
      (const __attribute__((address_space(1))) void*)g,
      (__attribute__((address_space(3))) void*)l, 16, 0, 0);
}
__device__ __forceinline__ void wait4() {
  asm volatile("s_waitcnt vmcnt(4)" ::: "memory");
  __builtin_amdgcn_sched_barrier(0);
}
__device__ __forceinline__ void wait0() {
  asm volatile("s_waitcnt vmcnt(0)" ::: "memory");
  __builtin_amdgcn_sched_barrier(0);
}

#define MFMA32(A, B, C) __builtin_amdgcn_mfma_f32_32x32x16_bf16((A), (B), (C), 0, 0, 0)

// ---------------- pre-pass: f32 K,V -> fragment-major bf16 images (unchanged) ----------------
__global__ __launch_bounds__(256)
void preconv(const float* __restrict__ Kg, const float* __restrict__ Vg) {
  const int bid = blockIdx.x;           // 1024 = 32 slices * 32 subtiles
  const int nh = bid >> 5;
  const int kt = bid & 31;
  const size_t base = (size_t)(nh >> 4) * Lseq * ROWS + (size_t)(nh & 15) * 64;
  const int tid = threadIdx.x;
  char* kimg = (char*)g_Kb + ((size_t)nh * 32 + kt) * 8192;
  char* vimg = (char*)g_Vb + ((size_t)nh * 32 + kt) * 8192;

#pragma unroll
  for (int p = 0; p < 2; ++p) {
    const int f    = tid + p * 256;      // fragment id 0..511
    const int half = f >> 8;
    const int c    = (f >> 6) & 3;
    const int hi   = (f >> 5) & 1;
    const int lq   = f & 31;
    {
      const float* src = Kg + base + (size_t)(kt * 64 + half * 32 + lq) * ROWS
                         + c * 16 + hi * 8;
      float4_t a = *(const float4_t*)src;
      float4_t b = *(const float4_t*)(src + 4);
      *(int4v*)(kimg + f * 16) = pk8(a, b);
    }
    {
      const float* src = Vg + base + (size_t)(kt * 64 + c * 16 + hi * 8) * ROWS
                         + half * 32 + lq;
      float v[8];
#pragma unroll
      for (int j = 0; j < 8; ++j) v[j] = src[(size_t)j * ROWS];
      int4v w;
      w[0] = cvtpk(v[0], v[1]); w[1] = cvtpk(v[2], v[3]);
      w[2] = cvtpk(v[4], v[5]); w[3] = cvtpk(v[6], v[7]);
      *(int4v*)(vimg + f * 16) = w;
    }
  }
}

// ---- main: 1024 blocks x 4 waves = 4096 waves (4/SIMD). Block = 64 q-rows.
//      Wave w: q-panel p=w&1 (32 rows), kv-half h=w>>1 (1024 rows, 32 steps x 32 kv).
//      p=0 waves DMA K chunks, p=1 waves DMA V chunks (4KB/step each).
//      LDS 32KB -> 4 blocks/CU -> 16 waves/CU. Counted vmcnt(4), raw s_barrier.
//      Row-sum on matrix pipe (lacc). h-pair merge via LDS at the end. ----
__global__ __launch_bounds__(256, 4)
void attn_fwd(const float* __restrict__ Qg, float* __restrict__ Og) {
  __shared__ __align__(16) short kv[2][2][2][2048];   // [h][buf][K,V][4KB] = 32 KB

  const int wg  = blockIdx.x;
  const int swz = (wg & 7) * 128 + (wg >> 3);   // XCD-bijective, nwg=1024
  const int nh  = swz >> 5;                     // 0..31
  const int qb  = swz & 31;                     // 64-row q block 0..31
  const size_t base = (size_t)(nh >> 4) * Lseq * ROWS + (size_t)(nh & 15) * 64;

  const int tid  = threadIdx.x;
  const int lane = tid & 63;
  const int wid  = tid >> 6;
  const int p    = wid & 1;      // q panel (also: 0 -> DMA K, 1 -> DMA V)
  const int h    = wid >> 1;     // kv half
  const int lq   = lane & 31;
  const int hi   = lane >> 5;

  // ---- Q B-fragments for panel p ----
  bf16x8 qf[4];
  {
    const float* qa = Qg + base + (size_t)(qb * 64 + p * 32 + lq) * ROWS + hi * 8;
#pragma unroll
    for (int c = 0; c < 4; ++c) {
      float4_t a = *(const float4_t*)(qa + c * 16);
      float4_t b = *(const float4_t*)(qa + c * 16 + 4);
#pragma unroll
      for (int j = 0; j < 4; ++j) { a[j] *= SCALE_LOG2E; b[j] *= SCALE_LOG2E; }
      qf[c] = __builtin_bit_cast(bf16x8, pk8(a, b));
    }
  }
  wait0();   // drain compiler-issued Q loads before the counted-DMA regime

  bf16x8 onesf;
#pragma unroll
  for (int j = 0; j < 8; ++j) onesf[j] = (short)0x3F80;   // bf16 1.0

  const char* kimg = (const char*)g_Kb + (size_t)nh * 262144;
  const char* vimg = (const char*)g_Vb + (size_t)nh * 262144;

  // stage step t (32 kv rows of half h) into buf b; this wave stages its operand
  auto stage = [&](int b, int t) {
    char* d = (char*)&kv[h][b][p][0];
    const size_t st = (size_t)(h * 16 + (t >> 1)) * 8192;
    if (p == 0) {
      // K: contiguous 4KB = frags [c=0..3] of the (t&1) 32-row half
      const char* s = kimg + st + (t & 1) * 4096 + lane * 16;
#pragma unroll
      for (int i = 0; i < 4; ++i) dma16(s + i * 1024, d + i * 1024);
    } else {
      // V: gather kv window (t&1)*32..+32 = c in {2(t&1), 2(t&1)+1} from both d-halves
      const char* s = vimg + st + (t & 1) * 2048 + lane * 16;
      dma16(s,               d);            // dhalf0 ks0
      dma16(s + 1024,        d + 1024);     // dhalf0 ks1
      dma16(s + 4096,        d + 2048);     // dhalf1 ks0
      dma16(s + 4096 + 1024, d + 3072);     // dhalf1 ks1
    }
  };

  stage(0, 0);
  stage(1, 1);   // queue: 8 outstanding (4 per step)

  f32x16 acc0 = {}, acc1 = {}, lacc = {};

#pragma unroll 1
  for (int t = 0; t < 32; ++t) {
    wait4();                                // my 4 DMAs of step t landed (t+1 in flight)
    __builtin_amdgcn_s_barrier();           // all 4 chunks of step t in LDS
    __builtin_amdgcn_sched_barrier(0);

    const int buf = t & 1;
    const char* kld = (const char*)&kv[h][buf][0][0] + lane * 16;
    const char* vld = (const char*)&kv[h][buf][1][0] + lane * 16;

    // ---- S^T (32 kv x 32 q) = K·Q ----
    f32x16 s = {};
#pragma unroll
    for (int c = 0; c < 4; ++c)
      s = MFMA32(*(const bf16x8*)(kld + c * 1024), qf[c], s);

    // ---- P = exp2(S); pack to 2 A-frags ----
#pragma unroll
    for (int r = 0; r < 16; ++r) s[r] = __builtin_amdgcn_exp2f(s[r]);
    bf16x8 pa[2];
#pragma unroll
    for (int c = 0; c < 2; ++c) {
      const int br = c * 8;
      int t0 = cvtpk(s[br + 0], s[br + 1]);
      int t1 = cvtpk(s[br + 2], s[br + 3]);
      int t2 = cvtpk(s[br + 4], s[br + 5]);
      int t3 = cvtpk(s[br + 6], s[br + 7]);
      plswap(t0, t2);
      plswap(t1, t3);
      int4v tt; tt[0] = t0; tt[1] = t1; tt[2] = t2; tt[3] = t3;
      pa[c] = __builtin_bit_cast(bf16x8, tt);
    }

    // ---- O += P·V ; row-sum on matrix pipe ----
#pragma unroll
    for (int ks = 0; ks < 2; ++ks) {
      acc0 = MFMA32(pa[ks], *(const bf16x8*)(vld + ks * 1024),        acc0);
      acc1 = MFMA32(pa[ks], *(const bf16x8*)(vld + 2048 + ks * 1024), acc1);
      lacc = MFMA32(pa[ks], onesf, lacc);
    }

    __builtin_amdgcn_sched_barrier(0);
    __builtin_amdgcn_s_barrier();           // all reads of buf done block-wide
    stage(buf, (t + 2) & 31);               // DMA step t+2 (wrap = harmless dummy)
  }
  wait0();   // drain the dummy wrap DMAs
  __builtin_amdgcn_s_barrier();             // everyone done with kv LDS

  // ---- h-pair merge via LDS scratch (reuse kv): h1 writes, h0 combines+stores ----
  float* scr = (float*)&kv[0][0][0][0] + p * 3072 + lane * 48;
  if (h == 1) {
#pragma unroll
    for (int r = 0; r < 16; ++r) {
      scr[r]      = acc0[r];
      scr[16 + r] = acc1[r];
      scr[32 + r] = lacc[r];
    }
  }
  __builtin_amdgcn_s_barrier();
  if (h == 0) {
#pragma unroll
    for (int r = 0; r < 16; ++r) {
      const int qr = (r & 3) + 8 * (r >> 2) + 4 * hi;
      const float li = 1.0f / (lacc[r] + scr[32 + r]);
      float* orow = Og + base + (size_t)(qb * 64 + p * 32 + qr) * ROWS;
      orow[lq]      = (acc0[r] + scr[r]) * li;
      orow[32 + lq] = (acc1[r] + scr[16 + r]) * li;
    }
  }
}

extern "C" void kernel_launch(void* const* d_in, const int* in_sizes, int n_in,
                              void* d_out, int out_size, void* d_ws, size_t ws_size,
                              hipStream_t stream) {
  const float* Q = (const float*)d_in[0];
  const float* K = (const float*)d_in[1];
  const float* V = (const float*)d_in[2];
  float* O = (float*)d_out;
  preconv<<<dim3(1024), dim3(256), 0, stream>>>(K, V);
  attn_fwd<<<dim3(1024), dim3(256), 0, stream>>>(Q, O);
}

// Round 20
// 58.322 us; speedup vs baseline: 1.0906x; 1.0906x over previous
//
#include <hip/hip_runtime.h>
#include <hip/hip_bf16.h>

typedef __attribute__((ext_vector_type(8))) short bf16x8;
typedef __attribute__((ext_vector_type(4))) float float4_t;
typedef __attribute__((ext_vector_type(16))) float f32x16;
typedef __attribute__((ext_vector_type(4))) int int4v;
typedef __attribute__((ext_vector_type(2))) int int2v;

constexpr int Lseq = 2048;
constexpr int ROWS = 1024;   // H*D floats between consecutive l for fixed (n,h)
constexpr float SCALE_LOG2E = 0.18033688011112042f;  // (1/sqrt(64))*log2(e)

// Fragment-major bf16 sub-images: per (nh, 64-row subtile): 512 frags x 16B = 8 KB.
// frag f = half*256 + c*64 + hi*32 + lq; K elem = K[sub*64+half*32+lq][c*16+hi*8+j],
// V elem = V^T[...] (rows=d, cols=kv within subtile).
__device__ short g_Kb[32 * 32 * 4096];   // 8 MB
__device__ short g_Vb[32 * 32 * 4096];   // 8 MB

__device__ __forceinline__ int cvtpk(float lo, float hi) {
  int r; asm("v_cvt_pk_bf16_f32 %0, %1, %2" : "=v"(r) : "v"(lo), "v"(hi)); return r;
}
__device__ __forceinline__ void plswap(int& a, int& b) {
  int2v r = __builtin_amdgcn_permlane32_swap(a, b, false, false);
  a = r[0]; b = r[1];
}
__device__ __forceinline__ int4v pk8(float4_t a, float4_t b) {
  int4v t;
  t[0] = cvtpk(a[0], a[1]); t[1] = cvtpk(a[2], a[3]);
  t[2] = cvtpk(b[0], b[1]); t[3] = cvtpk(b[2], b[3]);
  return t;
}
__device__ __forceinline__ void dma16(const void* g, void* l) {
  __builtin_amdgcn_global_load_lds(
      (const __attribute__((address_space(1))) void*)g,
      (__attribute__((address_space(3))) void*)l, 16, 0, 0);
}
__device__ __forceinline__ void wait8() {
  asm volatile("s_waitcnt vmcnt(8)" ::: "memory");
  __builtin_amdgcn_sched_barrier(0);
}
__device__ __forceinline__ void wait0() {
  asm volatile("s_waitcnt vmcnt(0)" ::: "memory");
  __builtin_amdgcn_sched_barrier(0);
}

#define MFMA32(A, B, C) __builtin_amdgcn_mfma_f32_32x32x16_bf16((A), (B), (C), 0, 0, 0)

// ---------------- pre-pass: f32 K,V -> fragment-major bf16 images ----------------
// Coalesced rewrite: K rows read 64B/thread contiguous; V rows read coalesced into
// padded LDS [64][68] (16B-aligned rows; transposed column reads conflict-free),
// frags written in 512B coalesced segments. Arithmetic identical (cvt_pk RNE).
__global__ __launch_bounds__(256)
void preconv(const float* __restrict__ Kg, const float* __restrict__ Vg) {
  __shared__ float vbuf[64][68];        // 17.4 KB; row base 272B -> 16B aligned
  const int bid = blockIdx.x;           // 1024 = 32 slices * 32 subtiles
  const int nh = bid >> 5;
  const int kt = bid & 31;
  const size_t base = (size_t)(nh >> 4) * Lseq * ROWS + (size_t)(nh & 15) * 64;
  const int tid = threadIdx.x;
  char* kimg = (char*)g_Kb + ((size_t)nh * 32 + kt) * 8192;
  char* vimg = (char*)g_Vb + ((size_t)nh * 32 + kt) * 8192;

  const int r  = tid >> 2;        // row 0..63
  const int qc = (tid & 3) * 16;  // col chunk base (16 floats)

  // ---- K: coalesced row read (4 thr x 64B per row) -> 2 frags each ----
  {
    const float* src = Kg + base + (size_t)(kt * 64 + r) * ROWS + qc;
    float4_t a = ((const float4_t*)src)[0];
    float4_t b = ((const float4_t*)src)[1];
    float4_t c = ((const float4_t*)src)[2];
    float4_t d = ((const float4_t*)src)[3];
    const int half = r >> 5, lq = r & 31, q = tid & 3;
    *(int4v*)(kimg + (half * 256 + q * 64 + lq) * 16)      = pk8(a, b);  // hi=0
    *(int4v*)(kimg + (half * 256 + q * 64 + 32 + lq) * 16) = pk8(c, d);  // hi=1
  }
  // ---- V: coalesced row read into LDS ----
  {
    const float* src = Vg + base + (size_t)(kt * 64 + r) * ROWS + qc;
    float4_t a = ((const float4_t*)src)[0];
    float4_t b = ((const float4_t*)src)[1];
    float4_t c = ((const float4_t*)src)[2];
    float4_t d = ((const float4_t*)src)[3];
    *(float4_t*)&vbuf[r][qc]      = a;
    *(float4_t*)&vbuf[r][qc + 4]  = b;
    *(float4_t*)&vbuf[r][qc + 8]  = c;
    *(float4_t*)&vbuf[r][qc + 12] = d;
  }
  __syncthreads();
  // ---- V^T frags from LDS columns (stride 68 -> banks 4j+col, conflict-free) ----
#pragma unroll
  for (int pp = 0; pp < 2; ++pp) {
    const int f    = tid + pp * 256;     // fragment id 0..511
    const int half = f >> 8;
    const int c    = (f >> 6) & 3;
    const int hi   = (f >> 5) & 1;
    const int lq   = f & 31;
    const int col  = half * 32 + lq;
    const int row0 = c * 16 + hi * 8;
    float v[8];
#pragma unroll
    for (int j = 0; j < 8; ++j) v[j] = vbuf[row0 + j][col];
    int4v w;
    w[0] = cvtpk(v[0], v[1]); w[1] = cvtpk(v[2], v[3]);
    w[2] = cvtpk(v[4], v[5]); w[3] = cvtpk(v[6], v[7]);
    *(int4v*)(vimg + f * 16) = w;
  }
}

// ---- main (r18, best passing: 47.0us, MfmaUtil 35%, conflicts 0): 512 blocks x 4 waves;
//      128 q-rows/block (one 32-row panel per wave). K-step = 128 rows; per step each
//      wave DMAs one 8KB chunk (w0/w1 K, w2/w3 V). Double-buffered 64KB LDS, counted
//      vmcnt(8), raw s_barrier. Row-sum via MFMA vs ones-fragment -> no cross-lane
//      merge. NO sched_group_barrier (r11/r17: SGB spills corrupt the vmcnt FIFO). ----
__global__ __launch_bounds__(256, 2)
void attn_fwd(const float* __restrict__ Qg, float* __restrict__ Og) {
  __shared__ __align__(16) short kv[2][4][4096];   // [buf][Klo,Khi,Vlo,Vhi][8KB] = 64 KB

  const int wg  = blockIdx.x;
  const int swz = (wg & 7) * 64 + (wg >> 3);    // XCD-bijective, nwg=512
  const int nh  = swz >> 4;                     // 0..31
  const int qb  = swz & 15;                     // q block 0..15 (128 rows)
  const size_t base = (size_t)(nh >> 4) * Lseq * ROWS + (size_t)(nh & 15) * 64;

  const int tid  = threadIdx.x;
  const int lane = tid & 63;
  const int wid  = tid >> 6;      // wave 0..3: q-panel wid; DMA chunk wid
  const int lq   = lane & 31;
  const int hi   = lane >> 5;

  // ---- Q B-fragments for this wave's 32 rows ----
  bf16x8 qf[4];
  {
    const float* qa = Qg + base + (size_t)(qb * 128 + wid * 32 + lq) * ROWS + hi * 8;
#pragma unroll
    for (int c = 0; c < 4; ++c) {
      float4_t a = *(const float4_t*)(qa + c * 16);
      float4_t b = *(const float4_t*)(qa + c * 16 + 4);
#pragma unroll
      for (int j = 0; j < 4; ++j) { a[j] *= SCALE_LOG2E; b[j] *= SCALE_LOG2E; }
      qf[c] = __builtin_bit_cast(bf16x8, pk8(a, b));
    }
  }
  wait0();   // drain compiler-issued Q loads before the counted-DMA regime

  // ones B-fragment (bf16 1.0 = 0x3F80) for the row-sum MFMA
  bf16x8 onesf;
#pragma unroll
  for (int j = 0; j < 8; ++j) onesf[j] = (short)0x3F80;

  // wave's DMA source: K image for wid 0/1, V image for wid 2/3 (lo/hi 64-row half)
  const char* gimg = ((wid < 2) ? (const char*)g_Kb : (const char*)g_Vb)
                     + (size_t)nh * 262144 + (size_t)(wid & 1) * 8192 + lane * 16;
  auto stage = [&](int buf, int t) {   // 8 x 1KB DMA chunks of step t's sub-image
    const char* s = gimg + (size_t)t * 16384;
    char* d = (char*)&kv[buf][wid][0];
#pragma unroll
    for (int i = 0; i < 8; ++i) dma16(s + i * 1024, d + i * 1024);
  };

  stage(0, 0);
  stage(1, 1);   // queue: 16 outstanding (8 per step)

  f32x16 acc0 = {}, acc1 = {}, lacc = {};
  bf16x8 pa[4];

  auto softmax_pa = [&](f32x16& s0, f32x16& s1) {   // exp2 + pack only (no row-sum)
#pragma unroll
    for (int r = 0; r < 16; ++r) {
      s0[r] = __builtin_amdgcn_exp2f(s0[r]);
      s1[r] = __builtin_amdgcn_exp2f(s1[r]);
    }
#pragma unroll
    for (int c = 0; c < 4; ++c) {
      const f32x16& sv = (c < 2) ? s0 : s1;
      const int br = (c & 1) * 8;
      int t0 = cvtpk(sv[br + 0], sv[br + 1]);
      int t1 = cvtpk(sv[br + 2], sv[br + 3]);
      int t2 = cvtpk(sv[br + 4], sv[br + 5]);
      int t3 = cvtpk(sv[br + 6], sv[br + 7]);
      plswap(t0, t2);
      plswap(t1, t3);
      int4v tt; tt[0] = t0; tt[1] = t1; tt[2] = t2; tt[3] = t3;
      pa[c] = __builtin_bit_cast(bf16x8, tt);
    }
  };

#pragma unroll 1
  for (int t = 0; t < 16; ++t) {
    wait8();                                // my chunk of step t landed (t+1 in flight)
    __builtin_amdgcn_s_barrier();           // all 4 chunks of step t in LDS
    __builtin_amdgcn_sched_barrier(0);

    const int buf = t & 1;
    // ---- two fence-free 64-row sub-tiles per step ----
#pragma unroll
    for (int s = 0; s < 2; ++s) {
      const char* kld = (const char*)&kv[buf][s][0]     + lane * 16;
      const char* vld = (const char*)&kv[buf][2 + s][0] + lane * 16;
      f32x16 s0 = {}, s1 = {};
#pragma unroll
      for (int c = 0; c < 4; ++c) {
        s0 = MFMA32(*(const bf16x8*)(kld + c * 1024),        qf[c], s0);
        s1 = MFMA32(*(const bf16x8*)(kld + 4096 + c * 1024), qf[c], s1);
      }
      softmax_pa(s0, s1);
#pragma unroll
      for (int c = 0; c < 4; ++c) {
        acc0 = MFMA32(pa[c], *(const bf16x8*)(vld + c * 1024),        acc0);
        acc1 = MFMA32(pa[c], *(const bf16x8*)(vld + 4096 + c * 1024), acc1);
        lacc = MFMA32(pa[c], onesf, lacc);   // row-sum on the matrix pipe
      }
    }

    __builtin_amdgcn_sched_barrier(0);
    __builtin_amdgcn_s_barrier();           // all reads of buf done block-wide
    stage(buf, (t + 2) & 15);               // DMA step t+2 (wrap = harmless dummy)
  }
  wait0();   // drain the dummy wrap DMAs

  // ---- normalize + store: lacc[r] is the full row sum for row qr (all cols equal) ----
#pragma unroll
  for (int r = 0; r < 16; ++r) {
    int qr = (r & 3) + 8 * (r >> 2) + 4 * hi;
    const float li = 1.0f / lacc[r];
    float* orow = Og + base + (size_t)(qb * 128 + wid * 32 + qr) * ROWS;
    orow[lq]      = acc0[r] * li;
    orow[32 + lq] = acc1[r] * li;
  }
}

extern "C" void kernel_launch(void* const* d_in, const int* in_sizes, int n_in,
                              void* d_out, int out_size, void* d_ws, size_t ws_size,
                              hipStream_t stream) {
  const float* Q = (const float*)d_in[0];
  const float* K = (const float*)d_in[1];
  const float* V = (const float*)d_in[2];
  float* O = (float*)d_out;
  preconv<<<dim3(1024), dim3(256), 0, stream>>>(K, V);
  attn_fwd<<<dim3(512), dim3(256), 0, stream>>>(Q, O);
}

// Round 21
// 56.355 us; speedup vs baseline: 1.1287x; 1.0349x over previous
//
#include <hip/hip_runtime.h>
#include <hip/hip_bf16.h>

typedef __attribute__((ext_vector_type(8))) short bf16x8;
typedef __attribute__((ext_vector_type(4))) float float4_t;
typedef __attribute__((ext_vector_type(2))) float f32x2;
typedef __attribute__((ext_vector_type(16))) float f32x16;
typedef __attribute__((ext_vector_type(4))) int int4v;
typedef __attribute__((ext_vector_type(2))) int int2v;

constexpr int Lseq = 2048;
constexpr int ROWS = 1024;   // H*D floats between consecutive l for fixed (n,h)
constexpr float SCALE_LOG2E = 0.18033688011112042f;  // (1/sqrt(64))*log2(e)

// Fragment-major bf16 sub-images: per (nh, 64-row subtile): 512 frags x 16B = 8 KB.
// frag f = half*256 + c*64 + hi*32 + lq; K elem = K[sub*64+half*32+lq][c*16+hi*8+j],
// V elem = V^T (rows=d, cols=kv within subtile).
__device__ short g_Kb[32 * 32 * 4096];   // 8 MB
__device__ short g_Vb[32 * 32 * 4096];   // 8 MB

__device__ __forceinline__ int cvtpk(float lo, float hi) {
  int r; asm("v_cvt_pk_bf16_f32 %0, %1, %2" : "=v"(r) : "v"(lo), "v"(hi)); return r;
}
__device__ __forceinline__ f32x2 pkadd(f32x2 a, f32x2 b) {
  f32x2 r; asm("v_pk_add_f32 %0, %1, %2" : "=v"(r) : "v"(a), "v"(b)); return r;
}
__device__ __forceinline__ void plswap(int& a, int& b) {
  int2v r = __builtin_amdgcn_permlane32_swap(a, b, false, false);
  a = r[0]; b = r[1];
}
__device__ __forceinline__ int4v pk8(float4_t a, float4_t b) {
  int4v t;
  t[0] = cvtpk(a[0], a[1]); t[1] = cvtpk(a[2], a[3]);
  t[2] = cvtpk(b[0], b[1]); t[3] = cvtpk(b[2], b[3]);
  return t;
}
__device__ __forceinline__ void dma16(const void* g, void* l) {
  __builtin_amdgcn_global_load_lds(
      (const __attribute__((address_space(1))) void*)g,
      (__attribute__((address_space(3))) void*)l, 16, 0, 0);
}
__device__ __forceinline__ void wait8() {
  asm volatile("s_waitcnt vmcnt(8)" ::: "memory");
  __builtin_amdgcn_sched_barrier(0);
}
__device__ __forceinline__ void wait0() {
  asm volatile("s_waitcnt vmcnt(0)" ::: "memory");
  __builtin_amdgcn_sched_barrier(0);
}

#define MFMA32(A, B, C) __builtin_amdgcn_mfma_f32_32x32x16_bf16((A), (B), (C), 0, 0, 0)

// ---------------- pre-pass (r20, coalesced): f32 K,V -> fragment-major bf16 images ----------------
__global__ __launch_bounds__(256)
void preconv(const float* __restrict__ Kg, const float* __restrict__ Vg) {
  __shared__ float vbuf[64][68];        // padded rows; 16B-aligned row base
  const int bid = blockIdx.x;           // 1024 = 32 slices * 32 subtiles
  const int nh = bid >> 5;
  const int kt = bid & 31;
  const size_t base = (size_t)(nh >> 4) * Lseq * ROWS + (size_t)(nh & 15) * 64;
  const int tid = threadIdx.x;
  char* kimg = (char*)g_Kb + ((size_t)nh * 32 + kt) * 8192;
  char* vimg = (char*)g_Vb + ((size_t)nh * 32 + kt) * 8192;

  const int r  = tid >> 2;        // row 0..63
  const int qc = (tid & 3) * 16;  // col chunk base (16 floats)

  // ---- K: coalesced row read (4 thr x 64B per row) -> 2 frags each ----
  {
    const float* src = Kg + base + (size_t)(kt * 64 + r) * ROWS + qc;
    float4_t a = ((const float4_t*)src)[0];
    float4_t b = ((const float4_t*)src)[1];
    float4_t c = ((const float4_t*)src)[2];
    float4_t d = ((const float4_t*)src)[3];
    const int half = r >> 5, lq = r & 31, q = tid & 3;
    *(int4v*)(kimg + (half * 256 + q * 64 + lq) * 16)      = pk8(a, b);  // hi=0
    *(int4v*)(kimg + (half * 256 + q * 64 + 32 + lq) * 16) = pk8(c, d);  // hi=1
  }
  // ---- V: coalesced row read into LDS ----
  {
    const float* src = Vg + base + (size_t)(kt * 64 + r) * ROWS + qc;
    float4_t a = ((const float4_t*)src)[0];
    float4_t b = ((const float4_t*)src)[1];
    float4_t c = ((const float4_t*)src)[2];
    float4_t d = ((const float4_t*)src)[3];
    *(float4_t*)&vbuf[r][qc]      = a;
    *(float4_t*)&vbuf[r][qc + 4]  = b;
    *(float4_t*)&vbuf[r][qc + 8]  = c;
    *(float4_t*)&vbuf[r][qc + 12] = d;
  }
  __syncthreads();
  // ---- V^T frags from LDS columns (stride 68: conflict-spread) ----
#pragma unroll
  for (int pp = 0; pp < 2; ++pp) {
    const int f    = tid + pp * 256;     // fragment id 0..511
    const int half = f >> 8;
    const int c    = (f >> 6) & 3;
    const int hi   = (f >> 5) & 1;
    const int lq   = f & 31;
    const int col  = half * 32 + lq;
    const int row0 = c * 16 + hi * 8;
    float v[8];
#pragma unroll
    for (int j = 0; j < 8; ++j) v[j] = vbuf[row0 + j][col];
    int4v w;
    w[0] = cvtpk(v[0], v[1]); w[1] = cvtpk(v[2], v[3]);
    w[2] = cvtpk(v[4], v[5]); w[3] = cvtpk(v[6], v[7]);
    *(int4v*)(vimg + f * 16) = w;
  }
}

// ---- main (r16, best measured): 512 blocks x 4 waves; 128 q-rows/block (one 32-row
//      panel per wave). K-step = 128 rows; per step each wave DMAs one 8KB chunk
//      (w0/w1 K, w2/w3 V). Double-buffered 64KB LDS, counted vmcnt(8), raw s_barrier.
//      pkadd row-sum. NO sched_group_barrier (r11/r17: SGB spills corrupt the
//      counted-vmcnt FIFO). Uniform dummy wrap DMAs are load-bearing for vmcnt. ----
__global__ __launch_bounds__(256, 2)
void attn_fwd(const float* __restrict__ Qg, float* __restrict__ Og) {
  __shared__ __align__(16) short kv[2][4][4096];   // [buf][Klo,Khi,Vlo,Vhi][8KB] = 64 KB

  const int wg  = blockIdx.x;
  const int swz = (wg & 7) * 64 + (wg >> 3);    // XCD-bijective, nwg=512
  const int nh  = swz >> 4;                     // 0..31
  const int qb  = swz & 15;                     // q block 0..15 (128 rows)
  const size_t base = (size_t)(nh >> 4) * Lseq * ROWS + (size_t)(nh & 15) * 64;

  const int tid  = threadIdx.x;
  const int lane = tid & 63;
  const int wid  = tid >> 6;      // wave 0..3: q-panel wid; DMA chunk wid
  const int lq   = lane & 31;
  const int hi   = lane >> 5;

  // ---- Q B-fragments for this wave's 32 rows ----
  bf16x8 qf[4];
  {
    const float* qa = Qg + base + (size_t)(qb * 128 + wid * 32 + lq) * ROWS + hi * 8;
#pragma unroll
    for (int c = 0; c < 4; ++c) {
      float4_t a = *(const float4_t*)(qa + c * 16);
      float4_t b = *(const float4_t*)(qa + c * 16 + 4);
#pragma unroll
      for (int j = 0; j < 4; ++j) { a[j] *= SCALE_LOG2E; b[j] *= SCALE_LOG2E; }
      qf[c] = __builtin_bit_cast(bf16x8, pk8(a, b));
    }
  }
  wait0();   // drain compiler-issued Q loads before the counted-DMA regime

  // wave's DMA source: K image for wid 0/1, V image for wid 2/3 (lo/hi 64-row half)
  const char* gimg = ((wid < 2) ? (const char*)g_Kb : (const char*)g_Vb)
                     + (size_t)nh * 262144 + (size_t)(wid & 1) * 8192 + lane * 16;
  auto stage = [&](int buf, int t) {   // 8 x 1KB DMA chunks of step t's sub-image
    const char* s = gimg + (size_t)t * 16384;
    char* d = (char*)&kv[buf][wid][0];
#pragma unroll
    for (int i = 0; i < 8; ++i) dma16(s + i * 1024, d + i * 1024);
  };

  stage(0, 0);
  stage(1, 1);   // queue: 16 outstanding (8 per step)

  float l = 0.f;
  f32x16 acc0 = {}, acc1 = {};
  bf16x8 pa[4];

  auto softmax_pa = [&](f32x16& s0, f32x16& s1) {
#pragma unroll
    for (int r = 0; r < 16; ++r) {
      s0[r] = __builtin_amdgcn_exp2f(s0[r]);
      s1[r] = __builtin_amdgcn_exp2f(s1[r]);
    }
#pragma unroll
    for (int c = 0; c < 4; ++c) {
      const f32x16& sv = (c < 2) ? s0 : s1;
      const int br = (c & 1) * 8;
      int t0 = cvtpk(sv[br + 0], sv[br + 1]);
      int t1 = cvtpk(sv[br + 2], sv[br + 3]);
      int t2 = cvtpk(sv[br + 4], sv[br + 5]);
      int t3 = cvtpk(sv[br + 6], sv[br + 7]);
      plswap(t0, t2);
      plswap(t1, t3);
      int4v tt; tt[0] = t0; tt[1] = t1; tt[2] = t2; tt[3] = t3;
      pa[c] = __builtin_bit_cast(bf16x8, tt);
    }
#define S2(v, i) (f32x2{(v)[2 * (i)], (v)[2 * (i) + 1]})
    f32x2 u0 = pkadd(S2(s0, 0), S2(s0, 1));
    f32x2 u1 = pkadd(S2(s0, 2), S2(s0, 3));
    f32x2 u2 = pkadd(S2(s0, 4), S2(s0, 5));
    f32x2 u3 = pkadd(S2(s0, 6), S2(s0, 7));
    f32x2 u4 = pkadd(S2(s1, 0), S2(s1, 1));
    f32x2 u5 = pkadd(S2(s1, 2), S2(s1, 3));
    f32x2 u6 = pkadd(S2(s1, 4), S2(s1, 5));
    f32x2 u7 = pkadd(S2(s1, 6), S2(s1, 7));
    u0 = pkadd(u0, u1); u2 = pkadd(u2, u3);
    u4 = pkadd(u4, u5); u6 = pkadd(u6, u7);
    u0 = pkadd(u0, u2); u4 = pkadd(u4, u6);
    u0 = pkadd(u0, u4);
    l += u0[0] + u0[1];
#undef S2
  };

#pragma unroll 1
  for (int t = 0; t < 16; ++t) {
    wait8();                                // my chunk of step t landed (t+1 in flight)
    __builtin_amdgcn_s_barrier();           // all 4 chunks of step t in LDS
    __builtin_amdgcn_sched_barrier(0);

    const int buf = t & 1;
    // ---- two fence-free 64-row sub-tiles per step ----
#pragma unroll
    for (int s = 0; s < 2; ++s) {
      const char* kld = (const char*)&kv[buf][s][0]     + lane * 16;
      const char* vld = (const char*)&kv[buf][2 + s][0] + lane * 16;
      f32x16 s0 = {}, s1 = {};
#pragma unroll
      for (int c = 0; c < 4; ++c) {
        s0 = MFMA32(*(const bf16x8*)(kld + c * 1024),        qf[c], s0);
        s1 = MFMA32(*(const bf16x8*)(kld + 4096 + c * 1024), qf[c], s1);
      }
      softmax_pa(s0, s1);
#pragma unroll
      for (int c = 0; c < 4; ++c) {
        acc0 = MFMA32(pa[c], *(const bf16x8*)(vld + c * 1024),        acc0);
        acc1 = MFMA32(pa[c], *(const bf16x8*)(vld + 4096 + c * 1024), acc1);
      }
    }

    __builtin_amdgcn_sched_barrier(0);
    __builtin_amdgcn_s_barrier();           // all reads of buf done block-wide
    stage(buf, (t + 2) & 15);               // DMA step t+2 (wrap = harmless dummy)
  }
  wait0();   // drain the dummy wrap DMAs

  // ---- merge cross-half l, normalize, store this wave's 32 rows ----
  {
    int a = __float_as_int(l), b = a;
    plswap(a, b);
    l = __int_as_float(a) + __int_as_float(b);
  }
  const float linv = 1.0f / l;
#pragma unroll
  for (int r = 0; r < 16; ++r) {
    int qr = (r & 3) + 8 * (r >> 2) + 4 * hi;
    float li = __shfl(linv, qr);   // row qr's sum lives in lane qr (both halves merged)
    float* orow = Og + base + (size_t)(qb * 128 + wid * 32 + qr) * ROWS;
    orow[lq]      = acc0[r] * li;
    orow[32 + lq] = acc1[r] * li;
  }
}

extern "C" void kernel_launch(void* const* d_in, const int* in_sizes, int n_in,
                              void* d_out, int out_size, void* d_ws, size_t ws_size,
                              hipStream_t stream) {
  const float* Q = (const float*)d_in[0];
  const float* K = (const float*)d_in[1];
  const float* V = (const float*)d_in[2];
  float* O = (float*)d_out;
  preconv<<<dim3(1024), dim3(256), 0, stream>>>(K, V);
  attn_fwd<<<dim3(512), dim3(256), 0, stream>>>(Q, O);
}